// Round 3
// baseline (136.538 us; speedup 1.0000x reference)
//
#include <hip/hip_runtime.h>
#include <hip/hip_bf16.h>
#include <stdint.h>

#define B_   1024
#define NN_  64
#define F_   128
#define DM_  512
#define DK_  256

typedef unsigned short u16;
using f32x4  = __attribute__((ext_vector_type(4))) float;
using bf16x8 = __attribute__((ext_vector_type(8))) short;

__device__ __forceinline__ uint32_t f2bf(float x) {
  uint32_t u = __builtin_bit_cast(uint32_t, x);
  return (u + 0x7fffu + ((u >> 16) & 1u)) >> 16;  // RNE bf16
}
__device__ __forceinline__ float bf2f(uint32_t us) {
  return __builtin_bit_cast(float, us << 16);
}
__device__ __forceinline__ void split_pack(float x, float y, uint32_t& hp, uint32_t& lp) {
  uint32_t hx = f2bf(x), hy = f2bf(y);
  uint32_t lx = f2bf(x - bf2f(hx)), ly = f2bf(y - bf2f(hy));
  hp = hx | (hy << 16);
  lp = lx | (ly << 16);
}
__device__ __forceinline__ void split1(float x, u16& h, u16& l) {
  uint32_t hx = f2bf(x);
  h = (u16)hx;
  l = (u16)f2bf(x - bf2f(hx));
}

// ---------------- K-1: detect mask dtype (byte-bool vs int32) ----------------
// Safe: reads only first 65536 bytes (valid under both hypotheses).
// int32 mask with values {0,1}: every byte at i%4!=0 is 0.
// byte mask: ~49k random nonzero bytes at those positions.
__global__ __launch_bounds__(1024) void k_maskdetect(
    const unsigned char* __restrict__ m, int* __restrict__ flag) {
  __shared__ int found;
  if (threadIdx.x == 0) found = 0;
  __syncthreads();
  int any = 0;
  for (int i = threadIdx.x; i < 65536; i += 1024)
    if ((i & 3) && m[i]) any = 1;
  if (any) atomicOr(&found, 1);
  __syncthreads();
  if (threadIdx.x == 0) *flag = found;  // 1 = byte mask, 0 = int32 mask
}

// ---------------- K0: wk_comb fold + weight hi/lo bf16 splits ----------------
__global__ __launch_bounds__(256) void k_prep(
    const float* __restrict__ wk, const float* __restrict__ wm,
    const float* __restrict__ wv, const float* __restrict__ fc_w,
    const float* __restrict__ m1_w, const float* __restrict__ m2_w,
    float* __restrict__ wkc,
    u16* __restrict__ wv_hi, u16* __restrict__ wv_lo,
    u16* __restrict__ fc_hi, u16* __restrict__ fc_lo,
    u16* __restrict__ m1_hi, u16* __restrict__ m1_lo,
    u16* __restrict__ m2_hi, u16* __restrict__ m2_lo) {
  int gtid = blockIdx.x * 256 + threadIdx.x;
  int nthr = gridDim.x * 256;
  if (gtid < 2 * DM_) {  // wk_comb[h][d] = sum_e wk[h,e,d]*wm[DK+e]
    int h = gtid >> 9, d = gtid & 511;
    const float* col = wk + h * DK_ * DM_ + d;
    float s = 0.f;
    for (int e = 0; e < DK_; ++e) s += col[e * DM_] * wm[DK_ + e];
    wkc[gtid] = s;
  }
  for (int i = gtid; i < DM_ * DM_; i += nthr) split1(wv[i], wv_hi[i], wv_lo[i]);
  for (int i = gtid; i < DM_ * DM_; i += nthr) split1(fc_w[i], fc_hi[i], fc_lo[i]);
  for (int i = gtid; i < F_ * (DM_ + F_); i += nthr) split1(m1_w[i], m1_hi[i], m1_lo[i]);
  for (int i = gtid; i < F_ * F_; i += nthr) split1(m2_w[i], m2_hi[i], m2_lo[i]);
}

// ---------------- K1: scores (fp32), softmax, attn-out, kbar (fp32->split) ----------------
__global__ __launch_bounds__(256) void k_attn(
    const float* __restrict__ seq, const float* __restrict__ seq_e,
    const float* __restrict__ seq_t, const float* __restrict__ seq_p,
    const void* __restrict__ mask_raw, const int* __restrict__ mflag,
    const float* __restrict__ wkc, float* __restrict__ attn_out,
    uint32_t* __restrict__ kbar_hi, uint32_t* __restrict__ kbar_lo) {
  __shared__ float wkcs[2][512];
  __shared__ float pds[4][2][64];
  __shared__ float attns[2][64];
  int tid = threadIdx.x;
  int b = blockIdx.x;
  for (int i = tid; i < 1024; i += 256) ((float*)wkcs)[i] = wkc[i];
  __syncthreads();

  // phase 1: wave w owns quarter w of the 512-dim concat; lane n owns row n
  int w = tid >> 6, n = tid & 63;
  const float* arr = (w == 0 ? seq : (w == 1 ? seq_e : (w == 2 ? seq_t : seq_p)));
  const float* row = arr + (b * 64 + n) * 128;
  const float* wk0 = &wkcs[0][w * 128];
  const float* wk1 = &wkcs[1][w * 128];
  float pd0 = 0.f, pd1 = 0.f;
  #pragma unroll 8
  for (int f = 0; f < 128; f += 4) {
    float4 v = *(const float4*)(row + f);
    pd0 += v.x * wk0[f] + v.y * wk0[f + 1] + v.z * wk0[f + 2] + v.w * wk0[f + 3];
    pd1 += v.x * wk1[f] + v.y * wk1[f + 1] + v.z * wk1[f + 2] + v.w * wk1[f + 3];
  }
  pds[w][0][n] = pd0;
  pds[w][1][n] = pd1;
  __syncthreads();

  // phase 2: softmax per head (waves 0,1 = heads 0,1)
  if (tid < 128) {
    int h = w;
    float s = pds[0][h][n] + pds[1][h][n] + pds[2][h][n] + pds[3][h][n];
    int mi = b * 64 + n;
    int mv = (*mflag) ? (int)((const unsigned char*)mask_raw)[mi]
                      : ((const int*)mask_raw)[mi];
    if (mv) s = -1e10f;
    float m = s;
    #pragma unroll
    for (int off = 32; off; off >>= 1) m = fmaxf(m, __shfl_xor(m, off));
    float p = expf(s - m);
    float ssum = p;
    #pragma unroll
    for (int off = 32; off; off >>= 1) ssum += __shfl_xor(ssum, off);
    float a = p / ssum;
    attns[h][n] = a;
    attn_out[(h * B_ + b) * 64 + n] = a;
  }
  __syncthreads();

  // phase 3: kbar[h][d] fp32; thread owns d-pair (2*tid, 2*tid+1); coalesced
  // column reads (lanes d-major) hit L2 (block just streamed these bytes)
  int part = tid >> 6;
  int f = (2 * tid) & 127;
  const float* colp =
      (part == 0 ? seq : (part == 1 ? seq_e : (part == 2 ? seq_t : seq_p))) +
      b * 64 * 128 + f;
  float a00 = 0.f, a01 = 0.f, a10 = 0.f, a11 = 0.f;
  #pragma unroll 8
  for (int j = 0; j < 64; ++j) {
    float2 v = *(const float2*)(colp + j * 128);
    float at0 = attns[0][j], at1 = attns[1][j];
    a00 += at0 * v.x; a01 += at0 * v.y;
    a10 += at1 * v.x; a11 += at1 * v.y;
  }
  uint32_t hp, lp;
  int base = b * 512;  // uint32 row (1024 u16 = [h0:512][h1:512])
  split_pack(a00, a01, hp, lp);
  kbar_hi[base + tid] = hp; kbar_lo[base + tid] = lp;
  split_pack(a10, a11, hp, lp);
  kbar_hi[base + 256 + tid] = hp; kbar_lo[base + 256 + tid] = lp;
}

// ------- split-bf16 MFMA tile: A[M,K] rm hi/lo planes, B[N,K] rm hi/lo planes -------
__device__ __forceinline__ f32x4 mfma_tile_split(
    const u16* __restrict__ Ahi, const u16* __restrict__ Alo, int lda,
    const u16* __restrict__ Bhi, const u16* __restrict__ Blo, int ldb, int K) {
  int l = threadIdx.x & 63;
  int r = l & 15, g = l >> 4;
  int offA = r * lda + g * 8;
  int offB = r * ldb + g * 8;
  f32x4 acc = {0.f, 0.f, 0.f, 0.f};
  for (int k = 0; k < K; k += 32) {
    bf16x8 ah = *(const bf16x8*)(Ahi + offA + k);
    bf16x8 al = *(const bf16x8*)(Alo + offA + k);
    bf16x8 bh = *(const bf16x8*)(Bhi + offB + k);
    bf16x8 bl = *(const bf16x8*)(Blo + offB + k);
    acc = __builtin_amdgcn_mfma_f32_16x16x32_bf16(ah, bh, acc, 0, 0, 0);
    acc = __builtin_amdgcn_mfma_f32_16x16x32_bf16(ah, bl, acc, 0, 0, 0);
    acc = __builtin_amdgcn_mfma_f32_16x16x32_bf16(al, bh, acc, 0, 0, 0);
  }
  return acc;
}

// ---------------- K2: out1[b, h*256+e] = kbar[b,h,:] . wv[h*256+e,:] ----------------
__global__ __launch_bounds__(256) void k_out1(
    const u16* __restrict__ kbar_hi, const u16* __restrict__ kbar_lo,
    const u16* __restrict__ wv_hi, const u16* __restrict__ wv_lo,
    u16* __restrict__ out1_hi, u16* __restrict__ out1_lo) {
  int h = blockIdx.z;
  int wid = threadIdx.x >> 6;
  int m0 = blockIdx.x * 32 + (wid >> 1) * 16;
  int n0 = blockIdx.y * 32 + (wid & 1) * 16;
  f32x4 acc = mfma_tile_split(kbar_hi + h * 512 + m0 * 1024,
                              kbar_lo + h * 512 + m0 * 1024, 1024,
                              wv_hi + (h * 256 + n0) * 512,
                              wv_lo + (h * 256 + n0) * 512, 512, 512);
  int l = threadIdx.x & 63, r = l & 15, g = l >> 4;
  #pragma unroll
  for (int i = 0; i < 4; ++i) {
    int m = m0 + g * 4 + i;
    int idx = m * 512 + h * 256 + n0 + r;
    split1(acc[i], out1_hi[idx], out1_lo[idx]);
  }
}

// ---------------- K3a: fc + bias + LeakyReLU + residual(q), fp32 out ----------------
__global__ __launch_bounds__(256) void k_fc(
    const u16* __restrict__ out1_hi, const u16* __restrict__ out1_lo,
    const u16* __restrict__ fc_hi, const u16* __restrict__ fc_lo,
    const float* __restrict__ fc_b,
    const float* __restrict__ src, const float* __restrict__ src_t,
    const float* __restrict__ src_p, float* __restrict__ fco) {
  int wid = threadIdx.x >> 6;
  int m0 = blockIdx.x * 32 + (wid >> 1) * 16;
  int n0 = blockIdx.y * 32 + (wid & 1) * 16;
  f32x4 acc = mfma_tile_split(out1_hi + m0 * 512, out1_lo + m0 * 512, 512,
                              fc_hi + n0 * 512, fc_lo + n0 * 512, 512, 512);
  int l = threadIdx.x & 63, r = l & 15, g = l >> 4;
  int nn = n0 + r;
  int part = nn >> 7, f = nn & 127;
  float bias = fc_b[nn];
  #pragma unroll
  for (int i = 0; i < 4; ++i) {
    int m = m0 + g * 4 + i;
    float c = acc[i] + bias;
    c = (c >= 0.f) ? c : 0.2f * c;  // LeakyReLU(0.2)
    float qv = 0.f;                 // q = concat(src, 0, src_t, src_p)
    if (part == 0) qv = src[m * 128 + f];
    else if (part == 2) qv = src_t[m * 128 + f];
    else if (part == 3) qv = src_p[m * 128 + f];
    fco[m * 512 + nn] = c + qv;
  }
}

// ---------------- K3b: LayerNorm + x = [ln_out, src] split hi/lo ----------------
__global__ __launch_bounds__(64) void k_ln(
    const float* __restrict__ fco, const float* __restrict__ ln_g,
    const float* __restrict__ ln_b, const float* __restrict__ src,
    u16* __restrict__ x_hi, u16* __restrict__ x_lo) {
  int b = blockIdx.x, l = threadIdx.x;
  float v[8];
  float s = 0.f, s2 = 0.f;
  #pragma unroll
  for (int j = 0; j < 8; ++j) {
    v[j] = fco[b * 512 + j * 64 + l];
    s += v[j]; s2 += v[j] * v[j];
  }
  #pragma unroll
  for (int off = 32; off; off >>= 1) { s += __shfl_xor(s, off); s2 += __shfl_xor(s2, off); }
  float mu = s * (1.f / 512.f);
  float var = s2 * (1.f / 512.f) - mu * mu;
  float rstd = rsqrtf(var + 1e-5f);
  #pragma unroll
  for (int j = 0; j < 8; ++j) {
    int idx = j * 64 + l;
    float o = (v[j] - mu) * rstd * ln_g[idx] + ln_b[idx];
    int xi = b * 640 + idx;
    split1(o, x_hi[xi], x_lo[xi]);
  }
  #pragma unroll
  for (int j = 0; j < 2; ++j) {
    int xi = b * 640 + 512 + j * 64 + l;
    split1(src[b * 128 + j * 64 + l], x_hi[xi], x_lo[xi]);
  }
}

// ---------------- K4: hdn = relu(x @ m1_w^T + m1_b), split hi/lo ----------------
__global__ __launch_bounds__(256) void k_m1(
    const u16* __restrict__ x_hi, const u16* __restrict__ x_lo,
    const u16* __restrict__ m1_hi, const u16* __restrict__ m1_lo,
    const float* __restrict__ m1_b,
    u16* __restrict__ hdn_hi, u16* __restrict__ hdn_lo) {
  int wid = threadIdx.x >> 6;
  int m0 = blockIdx.x * 32 + (wid >> 1) * 16;
  int n0 = blockIdx.y * 32 + (wid & 1) * 16;
  f32x4 acc = mfma_tile_split(x_hi + m0 * 640, x_lo + m0 * 640, 640,
                              m1_hi + n0 * 640, m1_lo + n0 * 640, 640, 640);
  int l = threadIdx.x & 63, r = l & 15, g = l >> 4;
  int nn = n0 + r;
  float bias = m1_b[nn];
  #pragma unroll
  for (int i = 0; i < 4; ++i) {
    int m = m0 + g * 4 + i;
    float o = fmaxf(acc[i] + bias, 0.f);
    int idx = m * 128 + nn;
    split1(o, hdn_hi[idx], hdn_lo[idx]);
  }
}

// ---------------- K5: z = hdn @ m2_w^T + m2_b (fp32 out) ----------------
__global__ __launch_bounds__(256) void k_m2(
    const u16* __restrict__ hdn_hi, const u16* __restrict__ hdn_lo,
    const u16* __restrict__ m2_hi, const u16* __restrict__ m2_lo,
    const float* __restrict__ m2_b, float* __restrict__ z) {
  int wid = threadIdx.x >> 6;
  int m0 = blockIdx.x * 32 + (wid >> 1) * 16;
  int n0 = blockIdx.y * 32 + (wid & 1) * 16;
  f32x4 acc = mfma_tile_split(hdn_hi + m0 * 128, hdn_lo + m0 * 128, 128,
                              m2_hi + n0 * 128, m2_lo + n0 * 128, 128, 128);
  int l = threadIdx.x & 63, r = l & 15, g = l >> 4;
  int nn = n0 + r;
  float bias = m2_b[nn];
  #pragma unroll
  for (int i = 0; i < 4; ++i) {
    int m = m0 + g * 4 + i;
    z[m * 128 + nn] = acc[i] + bias;
  }
}

extern "C" void kernel_launch(void* const* d_in, const int* in_sizes, int n_in,
                              void* d_out, int out_size, void* d_ws, size_t ws_size,
                              hipStream_t stream) {
  (void)in_sizes; (void)n_in; (void)out_size; (void)ws_size;
  const float* src   = (const float*)d_in[0];
  const float* src_t = (const float*)d_in[1];
  const float* src_p = (const float*)d_in[2];
  const float* seq   = (const float*)d_in[3];
  const float* seq_t = (const float*)d_in[4];
  const float* seq_e = (const float*)d_in[5];
  const float* seq_p = (const float*)d_in[6];
  const void*  mask  = d_in[7];
  // d_in[8] = wq : unused (score_q is constant per softmax row -> cancels)
  const float* wk   = (const float*)d_in[9];
  const float* wv   = (const float*)d_in[10];
  const float* wm   = (const float*)d_in[11];
  const float* fc_w = (const float*)d_in[12];
  const float* fc_b = (const float*)d_in[13];
  const float* ln_g = (const float*)d_in[14];
  const float* ln_b = (const float*)d_in[15];
  const float* m1_w = (const float*)d_in[16];
  const float* m1_b = (const float*)d_in[17];
  const float* m2_w = (const float*)d_in[18];
  const float* m2_b = (const float*)d_in[19];

  float* z_out    = (float*)d_out;
  float* attn_out = z_out + B_ * F_;  // output 1 at 131072

  char* ws = (char*)d_ws;
  float* wkc     = (float*)(ws + 0);           //    4096
  u16* wv_hi     = (u16*)(ws + 4096);          //  524288
  u16* wv_lo     = (u16*)(ws + 528384);        //  524288
  u16* fc_hi     = (u16*)(ws + 1052672);       //  524288
  u16* fc_lo     = (u16*)(ws + 1576960);       //  524288
  u16* m1_hi     = (u16*)(ws + 2101248);       //  163840
  u16* m1_lo     = (u16*)(ws + 2265088);       //  163840
  u16* m2_hi     = (u16*)(ws + 2428928);       //   32768
  u16* m2_lo     = (u16*)(ws + 2461696);       //   32768
  uint32_t* kbhi = (uint32_t*)(ws + 2494464);  // 2097152
  uint32_t* kblo = (uint32_t*)(ws + 4591616);  // 2097152
  u16* out1_hi   = (u16*)(ws + 6688768);       // 1048576
  u16* out1_lo   = (u16*)(ws + 7737344);       // 1048576
  float* fco     = (float*)(ws + 8785920);     // 2097152
  u16* x_hi      = (u16*)(ws + 10883072);      // 1310720
  u16* x_lo      = (u16*)(ws + 12193792);      // 1310720
  u16* hdn_hi    = (u16*)(ws + 13504512);      //  262144
  u16* hdn_lo    = (u16*)(ws + 13766656);      //  262144
  int* mflag     = (int*)(ws + 14028800);      //       4  (total ~14 MB)

  hipLaunchKernelGGL(k_maskdetect, dim3(1), dim3(1024), 0, stream,
                     (const unsigned char*)mask, mflag);
  hipLaunchKernelGGL(k_prep, dim3(256), dim3(256), 0, stream,
                     wk, wm, wv, fc_w, m1_w, m2_w, wkc,
                     wv_hi, wv_lo, fc_hi, fc_lo, m1_hi, m1_lo, m2_hi, m2_lo);
  hipLaunchKernelGGL(k_attn, dim3(1024), dim3(256), 0, stream,
                     seq, seq_e, seq_t, seq_p, mask, mflag, wkc,
                     attn_out, kbhi, kblo);
  hipLaunchKernelGGL(k_out1, dim3(32, 8, 2), dim3(256), 0, stream,
                     (const u16*)kbhi, (const u16*)kblo, wv_hi, wv_lo,
                     out1_hi, out1_lo);
  hipLaunchKernelGGL(k_fc, dim3(32, 16), dim3(256), 0, stream,
                     out1_hi, out1_lo, fc_hi, fc_lo, fc_b, src, src_t, src_p, fco);
  hipLaunchKernelGGL(k_ln, dim3(1024), dim3(64), 0, stream,
                     fco, ln_g, ln_b, src, x_hi, x_lo);
  hipLaunchKernelGGL(k_m1, dim3(32, 4), dim3(256), 0, stream,
                     x_hi, x_lo, m1_hi, m1_lo, m1_b, hdn_hi, hdn_lo);
  hipLaunchKernelGGL(k_m2, dim3(32, 4), dim3(256), 0, stream,
                     hdn_hi, hdn_lo, m2_hi, m2_lo, m2_b, z_out);
}